// Round 11
// baseline (80.086 us; speedup 1.0000x reference)
//
#include <hip/hip_runtime.h>
#include <hip/hip_bf16.h>
#include <math.h>

// Router: logits = X @ W^T + b ; top-2 over 64 experts; softmax over the 2; rest 0.
// X: [32768,1024] f32, W: [64,1024] f32, b: [64] f32, Out: [32768,64] f32.
//
// MFMA path: exact bf16 hi/lo split, 3-term product (hh + hl + lh). Near-tie
// tokens (3rd logit within TAU of v2) recomputed exactly by rescue kernel.
//
// Round-11: fatten per-request compute + kill W re-read chain + deepen X window.
//  - wave = 32 tokens (2 MFMA tiles), FULL K: no split-K, no barriers, no LDS
//    combine; epilogue fully wave-private (r5's verified 16-lane butterfly x2).
//  - W: 8 b128 loads/step feed 24 MFMA (2x tile reuse); triple-buffered VGPRs,
//    loaded 2 steps ahead. W traffic: 256 blocks x 256KB = 64 MB (was 512).
//  - X: global_load_lds into 6-deep per-tile LDS ring, staged 5 steps ahead,
//    pre-swizzled global source + XOR ds_read (r10-validated machinery).
//  - single-counter FIFO waits: steady s_waitcnt vmcnt(16) = {STAGE(s+3..s+4),
//    LDW(s+1)} outstanding; tail 12/8/8/0; prologue 8/12.
//  - grid 256 x 256thr (4 waves) = 1 block/CU; ~12KB X in flight per wave.
//
// A/B k-mapping: element j of lane l covers k = (l>>4)*8 + j, identical for A
// (in-register split) and B (pack_w) -> permutation-safe.
// C/D layout (m89-verified): col = lane&15, row = (lane>>4)*4 + reg.
//
// Requires ws_size >= 512 KB (cnt @0, list @256, Whi @256K, Wlo @384K).

typedef __attribute__((ext_vector_type(8))) short bf16x8;
typedef __attribute__((ext_vector_type(4))) float f32x4;

#define TOKENS 32768
#define DDIM   1024
#define TAU    1e-3f

#define WS_CNT_OFF   0
#define WS_LIST_OFF  256
#define WS_WHI_OFF   262144
#define WS_WLO_OFF   (262144 + 131072)

#define AS1 __attribute__((address_space(1)))
#define AS3 __attribute__((address_space(3)))

union FragU { bf16x8 v; unsigned int u[4]; };

__device__ inline unsigned int pk_bf16(float a, float b) {
    float2 f; f.x = a; f.y = b;
    __hip_bfloat162 h = __float22bfloat162_rn(f);
    union { __hip_bfloat162 h2; unsigned int u; } cv; cv.h2 = h;
    return cv.u;
}
__device__ inline float2 bf2f2(unsigned int u) {
    union { __hip_bfloat162 h2; unsigned int uu; } cv; cv.uu = u;
    return __bfloat1622float2(cv.h2);
}
__device__ inline void merge2(float& v1, int& i1, float& v2, int& i2,
                              float o1, int oi1, float o2, int oi2) {
    const bool b1 = (o1 > v1) || (o1 == v1 && oi1 < i1);
    if (b1) {
        const bool b2 = (v1 > o2) || (v1 == o2 && i1 < oi2);
        v2 = b2 ? v1 : o2;  i2 = b2 ? i1 : oi2;
        v1 = o1;            i1 = oi1;
    } else {
        const bool b2 = (o1 > v2) || (o1 == v2 && oi1 < i2);
        if (b2) { v2 = o1; i2 = oi1; }
    }
}

// ---- kernel 1: pack W into fragment-ordered bf16 hi/lo ----
__launch_bounds__(256)
__global__ void pack_w_kernel(const float* __restrict__ W,
                              unsigned int* __restrict__ Whi,
                              unsigned int* __restrict__ Wlo) {
    const int idx = blockIdx.x * 256 + threadIdx.x;     // 0..8191 = (s,n,l)
    const int l = idx & 63, n = (idx >> 6) & 3, s = idx >> 8;
    const int e  = n * 16 + (l & 15);
    const int k0 = s * 32 + (l >> 4) * 8;
    const float* p = W + e * DDIM + k0;
    const float4 a = *(const float4*)p;
    const float4 b = *(const float4*)(p + 4);
    const float f[8] = {a.x, a.y, a.z, a.w, b.x, b.y, b.z, b.w};
    unsigned int hu[4], lu[4];
    #pragma unroll
    for (int j = 0; j < 4; ++j) {
        const float x0 = f[2 * j], x1 = f[2 * j + 1];
        const unsigned int h = pk_bf16(x0, x1);
        const float2 hf = bf2f2(h);
        hu[j] = h;
        lu[j] = pk_bf16(x0 - hf.x, x1 - hf.y);
    }
    uint4 hv; hv.x = hu[0]; hv.y = hu[1]; hv.z = hu[2]; hv.w = hu[3];
    uint4 lv; lv.x = lu[0]; lv.y = lu[1]; lv.z = lu[2]; lv.w = lu[3];
    *(uint4*)(Whi + (size_t)idx * 4) = hv;
    *(uint4*)(Wlo + (size_t)idx * 4) = lv;
}

// ---- kernel 2: main MFMA router (2 tiles/wave, full-K, DMA ring) ----
__launch_bounds__(256, 1)
__global__ void router_mfma(const float* __restrict__ X,
                            const unsigned int* __restrict__ Whi,
                            const unsigned int* __restrict__ Wlo,
                            const float* __restrict__ Bv,
                            float* __restrict__ Out,
                            unsigned int* __restrict__ flagCnt,
                            int* __restrict__ flagList) {
    __shared__ __align__(16) char smem[4 * 2 * 6 * 2048];   // 96 KB: 4 waves x 2 tiles x ring6

    const int tid  = threadIdx.x;
    const int w    = tid >> 6;
    const int lane = tid & 63;
    const int rl   = lane & 15;      // A-row (token within tile) / C-col
    const int kg   = lane >> 4;      // k-group
    const int tokBase = blockIdx.x * 128 + w * 32;

    char* lt0 = smem + w * 24576;          // tile0 ring
    char* lt1 = lt0 + 12288;               // tile1 ring

    // stage source: pre-swizzled global chunk cb, linear LDS dest (r10-validated)
    const int cb   = (lane & 7) ^ ((lane >> 3) & 7);
    const int row0 = lane >> 3;
    const float* xs00 = X + (size_t)(tokBase +  0 + row0) * DDIM + cb * 4;
    const float* xs01 = X + (size_t)(tokBase +  8 + row0) * DDIM + cb * 4;
    const float* xs10 = X + (size_t)(tokBase + 16 + row0) * DDIM + cb * 4;
    const float* xs11 = X + (size_t)(tokBase + 24 + row0) * DDIM + cb * 4;

    // swizzled ds_read offsets for the A fragment (row rl, chunks 2kg, 2kg+1)
    const int dso0 = rl * 128 + (((kg * 2 + 0) ^ (rl & 7)) * 16);
    const int dso1 = rl * 128 + (((kg * 2 + 1) ^ (rl & 7)) * 16);

    const unsigned int* whp = Whi + (size_t)lane * 4;
    const unsigned int* wlp = Wlo + (size_t)lane * 4;

    f32x4 acc0[4] = {f32x4{0,0,0,0}, f32x4{0,0,0,0}, f32x4{0,0,0,0}, f32x4{0,0,0,0}};
    f32x4 acc1[4] = {f32x4{0,0,0,0}, f32x4{0,0,0,0}, f32x4{0,0,0,0}, f32x4{0,0,0,0}};
    FragU WhA[4], WlA[4], WhB[4], WlB[4], WhC[4], WlC[4];

#define DMA16(gp, lp) __builtin_amdgcn_global_load_lds((AS1 const void*)(gp), \
                                                       (AS3 void*)(lp), 16, 0, 0)
#define STAGE(s) do { \
        char* l0_ = lt0 + ((s) % 6) * 2048; \
        char* l1_ = lt1 + ((s) % 6) * 2048; \
        DMA16(xs00 + (s) * 32, l0_); \
        DMA16(xs01 + (s) * 32, l0_ + 1024); \
        DMA16(xs10 + (s) * 32, l1_); \
        DMA16(xs11 + (s) * 32, l1_ + 1024); \
    } while (0)

#define LDW(s, Wh, Wl) do { \
        _Pragma("unroll") for (int n_ = 0; n_ < 4; ++n_) { \
            const int off_ = (s) * 1024 + n_ * 256; \
            *(uint4*)&Wh[n_].u[0] = *(const uint4*)(whp + off_); \
            *(uint4*)&Wl[n_].u[0] = *(const uint4*)(wlp + off_); } \
    } while (0)

#define WAITVM(N) asm volatile("s_waitcnt vmcnt(" #N ")" ::: "memory")
#define SB() __builtin_amdgcn_sched_barrier(0)

#define CMT(xa, xb, Wh, Wl, accT) do { \
        FragU ah_, al_; \
        const float fx_[8] = {xa.x, xa.y, xa.z, xa.w, xb.x, xb.y, xb.z, xb.w}; \
        _Pragma("unroll") for (int j_ = 0; j_ < 4; ++j_) { \
            const unsigned int h_ = pk_bf16(fx_[2*j_], fx_[2*j_+1]); \
            const float2 hf_ = bf2f2(h_); \
            ah_.u[j_] = h_; \
            al_.u[j_] = pk_bf16(fx_[2*j_] - hf_.x, fx_[2*j_+1] - hf_.y); } \
        _Pragma("unroll") for (int n_ = 0; n_ < 4; ++n_) { \
            accT[n_] = __builtin_amdgcn_mfma_f32_16x16x32_bf16(ah_.v, Wh[n_].v, accT[n_], 0, 0, 0); \
            accT[n_] = __builtin_amdgcn_mfma_f32_16x16x32_bf16(ah_.v, Wl[n_].v, accT[n_], 0, 0, 0); \
            accT[n_] = __builtin_amdgcn_mfma_f32_16x16x32_bf16(al_.v, Wh[n_].v, accT[n_], 0, 0, 0); } \
    } while (0)

// BODY(s): wait -> ds_read(s) -> LDW(s+2) -> STAGE(s+5) -> convert+MFMA(s)
#define BODY(s, VC, WhU, WlU, WhN, WlN, HASW, HASX) do { \
        WAITVM(VC); \
        SB(); \
        const char* b0_ = lt0 + ((s) % 6) * 2048; \
        const char* b1_ = lt1 + ((s) % 6) * 2048; \
        const float4 x00_ = *(const float4*)(b0_ + dso0); \
        const float4 x01_ = *(const float4*)(b0_ + dso1); \
        const float4 x10_ = *(const float4*)(b1_ + dso0); \
        const float4 x11_ = *(const float4*)(b1_ + dso1); \
        SB(); \
        if (HASW) LDW((s) + 2, WhN, WlN); \
        if (HASX) STAGE((s) + 5); \
        SB(); \
        CMT(x00_, x01_, WhU, WlU, acc0); \
        CMT(x10_, x11_, WhU, WlU, acc1); \
    } while (0)

    // Prologue: fill X ring 5 deep, W 2 deep.
    STAGE(0); STAGE(1); STAGE(2); STAGE(3); STAGE(4);
    SB();
    LDW(0, WhA, WlA);
    LDW(1, WhB, WlB);
    SB();

    BODY(0,  8, WhA, WlA, WhC, WlC, 1, 1);
    BODY(1, 12, WhB, WlB, WhA, WlA, 1, 1);
    BODY(2, 16, WhC, WlC, WhB, WlB, 1, 1);
    BODY(3, 16, WhA, WlA, WhC, WlC, 1, 1);
    BODY(4, 16, WhB, WlB, WhA, WlA, 1, 1);
    BODY(5, 16, WhC, WlC, WhB, WlB, 1, 1);

    #pragma unroll 1
    for (int su = 6; su <= 18; su += 6) {
        BODY(su + 0, 16, WhA, WlA, WhC, WlC, 1, 1);
        BODY(su + 1, 16, WhB, WlB, WhA, WlA, 1, 1);
        BODY(su + 2, 16, WhC, WlC, WhB, WlB, 1, 1);
        BODY(su + 3, 16, WhA, WlA, WhC, WlC, 1, 1);
        BODY(su + 4, 16, WhB, WlB, WhA, WlA, 1, 1);
        BODY(su + 5, 16, WhC, WlC, WhB, WlB, 1, 1);
    }

    BODY(24, 16, WhA, WlA, WhC, WlC, 1, 1);
    BODY(25, 16, WhB, WlB, WhA, WlA, 1, 1);
    BODY(26, 16, WhC, WlC, WhB, WlB, 1, 1);
    BODY(27, 16, WhA, WlA, WhC, WlC, 1, 0);
    BODY(28, 12, WhB, WlB, WhA, WlA, 1, 0);
    BODY(29,  8, WhC, WlC, WhB, WlB, 1, 0);
    BODY(30,  8, WhA, WlA, WhC, WlC, 0, 0);
    BODY(31,  0, WhB, WlB, WhC, WlC, 0, 0);

#undef DMA16
#undef STAGE
#undef LDW
#undef WAITVM
#undef SB
#undef CMT
#undef BODY

    // ---- wave-private epilogue: per tile, bias + top-2 + softmax + write ----
    float bv[4];
    #pragma unroll
    for (int n = 0; n < 4; ++n) bv[n] = Bv[n * 16 + rl];

    #pragma unroll
    for (int t = 0; t < 2; ++t) {
        #pragma unroll
        for (int r = 0; r < 4; ++r) {
            float v[4];
            #pragma unroll
            for (int n = 0; n < 4; ++n)
                v[n] = (t == 0 ? acc0[n][r] : acc1[n][r]) + bv[n];

            // in-lane top-2 over this lane's 4 experts (e = n*16 + rl)
            float v1 = -INFINITY, v2 = -INFINITY;
            int i1 = 0x7fffffff, i2 = 0x7fffffff;
            #pragma unroll
            for (int n = 0; n < 4; ++n) {
                const float val = v[n];
                const int   e   = n * 16 + rl;
                if (val > v1 || (val == v1 && e < i1)) { v2 = v1; i2 = i1; v1 = val; i1 = e; }
                else if (val > v2 || (val == v2 && e < i2)) { v2 = val; i2 = e; }
            }
            // butterfly across the 16 lanes of this kg group (lex: value desc, idx asc)
            #pragma unroll
            for (int st = 1; st <= 8; st <<= 1) {
                const float o1 = __shfl_xor(v1, st); const int oi1 = __shfl_xor(i1, st);
                const float o2 = __shfl_xor(v2, st); const int oi2 = __shfl_xor(i2, st);
                merge2(v1, i1, v2, i2, o1, oi1, o2, oi2);
            }
            // near-tie flag: any 3rd logit within TAU of v2?
            int cnt = 0;
            #pragma unroll
            for (int n = 0; n < 4; ++n) cnt += (v[n] > v2 - TAU) ? 1 : 0;
            cnt += __shfl_xor(cnt, 1);
            cnt += __shfl_xor(cnt, 2);
            cnt += __shfl_xor(cnt, 4);
            cnt += __shfl_xor(cnt, 8);

            const int T = tokBase + t * 16 + kg * 4 + r;
            if (rl == 0 && cnt > 2) {
                const unsigned int pos = atomicAdd(flagCnt, 1u);
                if (pos < TOKENS) flagList[pos] = T;
            }
            const float ex = expf(v2 - v1);      // <= 1
            const float w1 = 1.f / (1.f + ex);
            const float w2 = ex * w1;
            const int e0 = rl * 4;
            float4 o;
            o.x = (e0 + 0 == i1) ? w1 : ((e0 + 0 == i2) ? w2 : 0.f);
            o.y = (e0 + 1 == i1) ? w1 : ((e0 + 1 == i2) ? w2 : 0.f);
            o.z = (e0 + 2 == i1) ? w1 : ((e0 + 2 == i2) ? w2 : 0.f);
            o.w = (e0 + 3 == i1) ? w1 : ((e0 + 3 == i2) ? w2 : 0.f);
            *(float4*)(Out + (size_t)T * 64 + e0) = o;
        }
    }
}

// ---- kernel 3: exact fp32 rescue for near-tie tokens ----
__launch_bounds__(64)
__global__ void rescue_kernel(const float* __restrict__ X,
                              const float* __restrict__ W,
                              const float* __restrict__ Bv,
                              float* __restrict__ Out,
                              const unsigned int* __restrict__ flagCnt,
                              const int* __restrict__ flagList) {
    __shared__ float sx[DDIM];
    const int lane = threadIdx.x;
    unsigned int n = *flagCnt;
    if (n > TOKENS) n = TOKENS;
    for (unsigned int i = blockIdx.x; i < n; i += gridDim.x) {
        const int t = flagList[i];
        __syncthreads();
        #pragma unroll
        for (int k = 0; k < 4; ++k)
            ((float4*)sx)[lane + 64 * k] =
                ((const float4*)(X + (size_t)t * DDIM))[lane + 64 * k];
        __syncthreads();
        float acc = Bv[lane];
        const float* wr = W + (size_t)lane * DDIM;
        #pragma unroll 4
        for (int d = 0; d < DDIM; d += 4) {
            const float4 wv = *(const float4*)(wr + d);
            acc = fmaf(sx[d + 0], wv.x, acc);
            acc = fmaf(sx[d + 1], wv.y, acc);
            acc = fmaf(sx[d + 2], wv.z, acc);
            acc = fmaf(sx[d + 3], wv.w, acc);
        }
        float v1 = acc, v2 = -INFINITY;
        int i1 = lane, i2 = 0x7fffffff;
        #pragma unroll
        for (int st = 1; st <= 32; st <<= 1) {
            const float o1 = __shfl_xor(v1, st); const int oi1 = __shfl_xor(i1, st);
            const float o2 = __shfl_xor(v2, st); const int oi2 = __shfl_xor(i2, st);
            merge2(v1, i1, v2, i2, o1, oi1, o2, oi2);
        }
        const float ex = expf(v2 - v1);
        const float w1 = 1.f / (1.f + ex);
        const float w2 = ex * w1;
        Out[(size_t)t * 64 + lane] = (lane == i1) ? w1 : ((lane == i2) ? w2 : 0.f);
    }
}

extern "C" void kernel_launch(void* const* d_in, const int* in_sizes, int n_in,
                              void* d_out, int out_size, void* d_ws, size_t ws_size,
                              hipStream_t stream) {
    const float* X  = (const float*)d_in[0];   // [32768, 1024]
    const float* W  = (const float*)d_in[1];   // [64, 1024]
    const float* Bv = (const float*)d_in[2];   // [64]
    float* Out = (float*)d_out;                // [32768, 64]

    unsigned char* ws = (unsigned char*)d_ws;
    unsigned int* cnt  = (unsigned int*)(ws + WS_CNT_OFF);
    int*          list = (int*)(ws + WS_LIST_OFF);
    unsigned int* Whi  = (unsigned int*)(ws + WS_WHI_OFF);
    unsigned int* Wlo  = (unsigned int*)(ws + WS_WLO_OFF);

    hipMemsetAsync(cnt, 0, 4, stream);
    hipLaunchKernelGGL(pack_w_kernel, dim3(32), dim3(256), 0, stream, W, Whi, Wlo);
    hipLaunchKernelGGL(router_mfma, dim3(TOKENS / 128), dim3(256), 0, stream,
                       X, Whi, Wlo, Bv, Out, cnt, list);
    hipLaunchKernelGGL(rescue_kernel, dim3(512), dim3(64), 0, stream,
                       X, W, Bv, Out, cnt, list);
}

// Round 12
// 67.624 us; speedup vs baseline: 1.1843x; 1.1843x over previous
//
#include <hip/hip_runtime.h>
#include <hip/hip_bf16.h>
#include <math.h>

// Router: logits = X @ W^T + b ; top-2 over 64 experts; softmax over the 2; rest 0.
// X: [32768,1024] f32, W: [64,1024] f32, b: [64] f32, Out: [32768,64] f32.
//
// MFMA path: exact bf16 hi/lo split, 3-term product (hh + hl + lh). Near-tie
// tokens (3rd logit within TAU of v2) recomputed exactly by rescue kernel.
//
// Round-12: row-contiguous cooperative staging + LDS-shared W + 8 waves/CU.
//  Block = 4 waves x 64 tokens; wave w owns tile w (16 tokens, all 64 experts,
//  full K -> wave-private epilogue, zero combine). 16 phases of k=64:
//   - X: 64 rows x 256B CONTIGUOUS per row per phase (vs 128B scattered before;
//     attacks DRAM page thrash from 32K interleaved fine-grained row streams).
//   - W: 16 KB/phase staged ONCE per block into LDS, shared by 4 waves
//     (W traffic 512 MB -> 128 MB).
//   - double-buffered (64 KB LDS total) -> 2 blocks/CU = 8 waves/CU.
//   - raw s_barrier + per-wave counted vmcnt(8) (each wave waits only its own
//     8 DMAs; barrier upgrades to block-wide guarantee). Drain only at tail.
//   - X ds_reads XOR-swizzled via pre-swizzled GLOBAL source (r10-validated);
//     W LDS reads lane*16-contiguous (conflict-free, no swizzle needed).
//
// A/B k-mapping: element j of lane l covers k = (l>>4)*8 + j, identical for A
// (in-register split) and B (pack_w) -> permutation-safe.
// C/D layout (m89-verified): col = lane&15, row = (lane>>4)*4 + reg.
//
// Requires ws_size >= 512 KB (cnt @0, list @256, Whi @256K, Wlo @384K).

typedef __attribute__((ext_vector_type(8))) short bf16x8;
typedef __attribute__((ext_vector_type(4))) float f32x4;

#define TOKENS 32768
#define DDIM   1024
#define TAU    1e-3f

#define WS_CNT_OFF   0
#define WS_LIST_OFF  256
#define WS_WHI_OFF   262144
#define WS_WLO_OFF   (262144 + 131072)

#define AS1 __attribute__((address_space(1)))
#define AS3 __attribute__((address_space(3)))

union FragU { bf16x8 v; unsigned int u[4]; };
union FragU4 { bf16x8 v; uint4 q; };

__device__ inline unsigned int pk_bf16(float a, float b) {
    float2 f; f.x = a; f.y = b;
    __hip_bfloat162 h = __float22bfloat162_rn(f);
    union { __hip_bfloat162 h2; unsigned int u; } cv; cv.h2 = h;
    return cv.u;
}
__device__ inline float2 bf2f2(unsigned int u) {
    union { __hip_bfloat162 h2; unsigned int uu; } cv; cv.uu = u;
    return __bfloat1622float2(cv.h2);
}
__device__ inline void merge2(float& v1, int& i1, float& v2, int& i2,
                              float o1, int oi1, float o2, int oi2) {
    const bool b1 = (o1 > v1) || (o1 == v1 && oi1 < i1);
    if (b1) {
        const bool b2 = (v1 > o2) || (v1 == o2 && i1 < oi2);
        v2 = b2 ? v1 : o2;  i2 = b2 ? i1 : oi2;
        v1 = o1;            i1 = oi1;
    } else {
        const bool b2 = (o1 > v2) || (o1 == v2 && oi1 < i2);
        if (b2) { v2 = o1; i2 = oi1; }
    }
}

// ---- kernel 1: pack W into fragment-ordered bf16 hi/lo ----
__launch_bounds__(256)
__global__ void pack_w_kernel(const float* __restrict__ W,
                              unsigned int* __restrict__ Whi,
                              unsigned int* __restrict__ Wlo) {
    const int idx = blockIdx.x * 256 + threadIdx.x;     // 0..8191 = (s,n,l)
    const int l = idx & 63, n = (idx >> 6) & 3, s = idx >> 8;
    const int e  = n * 16 + (l & 15);
    const int k0 = s * 32 + (l >> 4) * 8;
    const float* p = W + e * DDIM + k0;
    const float4 a = *(const float4*)p;
    const float4 b = *(const float4*)(p + 4);
    const float f[8] = {a.x, a.y, a.z, a.w, b.x, b.y, b.z, b.w};
    unsigned int hu[4], lu[4];
    #pragma unroll
    for (int j = 0; j < 4; ++j) {
        const float x0 = f[2 * j], x1 = f[2 * j + 1];
        const unsigned int h = pk_bf16(x0, x1);
        const float2 hf = bf2f2(h);
        hu[j] = h;
        lu[j] = pk_bf16(x0 - hf.x, x1 - hf.y);
    }
    uint4 hv; hv.x = hu[0]; hv.y = hu[1]; hv.z = hu[2]; hv.w = hu[3];
    uint4 lv; lv.x = lu[0]; lv.y = lu[1]; lv.z = lu[2]; lv.w = lu[3];
    *(uint4*)(Whi + (size_t)idx * 4) = hv;
    *(uint4*)(Wlo + (size_t)idx * 4) = lv;
}

// ---- kernel 2: main MFMA router (cooperative phases, LDS-shared W) ----
__launch_bounds__(256, 2)
__global__ void router_mfma(const float* __restrict__ X,
                            const unsigned int* __restrict__ Whi,
                            const unsigned int* __restrict__ Wlo,
                            const float* __restrict__ Bv,
                            float* __restrict__ Out,
                            unsigned int* __restrict__ flagCnt,
                            int* __restrict__ flagList) {
    // [0,32K): X dbuf (2 x 64 rows x 256B). [32K,64K): W dbuf (2 x (hi 8K + lo 8K)).
    __shared__ __align__(16) char smem[65536];

    const int tid  = threadIdx.x;
    const int w    = tid >> 6;
    const int lane = tid & 63;
    const int rl   = lane & 15;      // A-row (token in tile) / C-col
    const int kg   = lane >> 4;      // k-group
    const int dr   = lane >> 4;      // staging row-within-group
    const int tokBase = blockIdx.x * 64;

    // --- X staging sources (pre-swizzled chunk; dest linear) ---
    // instr ii covers rows w*16 + ii*4 + dr; swizzle key = (ii*4+dr)&7:
    // ii even -> dr, ii odd -> dr^4.
    const float* xsE = X + (size_t)(tokBase + w * 16 + dr) * DDIM
                         + (((lane & 15) ^ dr) * 4);
    const float* xsO = X + (size_t)(tokBase + w * 16 + dr) * DDIM
                         + (((lane & 15) ^ (dr ^ 4)) * 4);
    const unsigned int* whs = Whi + lane * 4;   // +lane*16B
    const unsigned int* wls = Wlo + lane * 4;

    // --- A-frag swizzled ds_read offsets ---
    const int r7     = rl & 7;
    const int rowoff = w * 4096 + rl * 256;
    const int q0     = ((kg * 2 + 0) ^ r7) * 16;
    const int q1     = ((kg * 2 + 1) ^ r7) * 16;
    const int wlds   = lane * 16;

    f32x4 acc[4] = {f32x4{0,0,0,0}, f32x4{0,0,0,0}, f32x4{0,0,0,0}, f32x4{0,0,0,0}};

#define DMA16(gp, lp) __builtin_amdgcn_global_load_lds((AS1 const void*)(gp), \
                                                       (AS3 void*)(lp), 16, 0, 0)
#define WAITVM(N) asm volatile("s_waitcnt vmcnt(" #N ")" ::: "memory")
#define SB() __builtin_amdgcn_sched_barrier(0)

    auto ISSUE = [&](int p, const float* xE, const float* xO,
                     const unsigned int* wh, const unsigned int* wl) {
        char* xb = smem + ((p & 1) ? 16384 : 0) + w * 4096;
        DMA16(xE,         xb);
        DMA16(xO + 4096,  xb + 1024);
        DMA16(xE + 8192,  xb + 2048);
        DMA16(xO + 12288, xb + 3072);
        char* wb = smem + 32768 + ((p & 1) ? 16384 : 0);
        DMA16(wh + (w * 2 + 0) * 256, wb + (w * 2 + 0) * 1024);
        DMA16(wh + (w * 2 + 1) * 256, wb + (w * 2 + 1) * 1024);
        DMA16(wl + (w * 2 + 0) * 256, wb + 8192 + (w * 2 + 0) * 1024);
        DMA16(wl + (w * 2 + 1) * 256, wb + 8192 + (w * 2 + 1) * 1024);
    };

    auto CONSUME = [&](int p) {
        const char* xb = smem + ((p & 1) ? 16384 : 0);
        const char* wb = smem + 32768 + ((p & 1) ? 16384 : 0);
        #pragma unroll
        for (int sl = 0; sl < 2; ++sl) {
            const float4 x0 = *(const float4*)(xb + rowoff + sl * 128 + q0);
            const float4 x1 = *(const float4*)(xb + rowoff + sl * 128 + q1);
            FragU4 bh[4], bl[4];
            #pragma unroll
            for (int n = 0; n < 4; ++n) {
                bh[n].q = *(const uint4*)(wb + (sl * 4 + n) * 1024 + wlds);
                bl[n].q = *(const uint4*)(wb + 8192 + (sl * 4 + n) * 1024 + wlds);
            }
            FragU ah, al;
            const float fx[8] = {x0.x, x0.y, x0.z, x0.w, x1.x, x1.y, x1.z, x1.w};
            #pragma unroll
            for (int j = 0; j < 4; ++j) {
                const unsigned int h = pk_bf16(fx[2 * j], fx[2 * j + 1]);
                const float2 hf = bf2f2(h);
                ah.u[j] = h;
                al.u[j] = pk_bf16(fx[2 * j] - hf.x, fx[2 * j + 1] - hf.y);
            }
            #pragma unroll
            for (int n = 0; n < 4; ++n) {
                acc[n] = __builtin_amdgcn_mfma_f32_16x16x32_bf16(ah.v, bh[n].v, acc[n], 0, 0, 0);
                acc[n] = __builtin_amdgcn_mfma_f32_16x16x32_bf16(ah.v, bl[n].v, acc[n], 0, 0, 0);
                acc[n] = __builtin_amdgcn_mfma_f32_16x16x32_bf16(al.v, bh[n].v, acc[n], 0, 0, 0);
            }
        }
    };

    // Prologue: phases 0 and 1 in flight (8 DMA each per wave).
    ISSUE(0, xsE, xsO, whs, wls);
    ISSUE(1, xsE + 64, xsO + 64, whs + 2048, wls + 2048);
    const float* xE2 = xsE + 128;
    const float* xO2 = xsO + 128;
    const unsigned int* wh2 = whs + 4096;
    const unsigned int* wl2 = wls + 4096;

    #pragma unroll 1
    for (int p = 0; p < 15; ++p) {
        WAITVM(8);                       // own phase-p DMAs done; p+1 in flight
        __builtin_amdgcn_s_barrier();    // -> block-wide: phase p fully in LDS
        SB();
        CONSUME(p);
        SB();
        __builtin_amdgcn_s_barrier();    // all reads of slot (p&1) done
        if (p < 14) {
            ISSUE(p + 2, xE2, xO2, wh2, wl2);
            xE2 += 64; xO2 += 64; wh2 += 2048; wl2 += 2048;
        }
    }
    WAITVM(0);
    __builtin_amdgcn_s_barrier();
    SB();
    CONSUME(15);

#undef DMA16
#undef WAITVM
#undef SB

    // ---- wave-private epilogue: bias + top-2 + softmax + write (tile w) ----
    float bv[4];
    #pragma unroll
    for (int n = 0; n < 4; ++n) bv[n] = Bv[n * 16 + rl];

    #pragma unroll
    for (int r = 0; r < 4; ++r) {
        float v[4];
        #pragma unroll
        for (int n = 0; n < 4; ++n) v[n] = acc[n][r] + bv[n];

        float v1 = -INFINITY, v2 = -INFINITY;
        int i1 = 0x7fffffff, i2 = 0x7fffffff;
        #pragma unroll
        for (int n = 0; n < 4; ++n) {
            const float val = v[n];
            const int   e   = n * 16 + rl;
            if (val > v1 || (val == v1 && e < i1)) { v2 = v1; i2 = i1; v1 = val; i1 = e; }
            else if (val > v2 || (val == v2 && e < i2)) { v2 = val; i2 = e; }
        }
        #pragma unroll
        for (int st = 1; st <= 8; st <<= 1) {
            const float o1 = __shfl_xor(v1, st); const int oi1 = __shfl_xor(i1, st);
            const float o2 = __shfl_xor(v2, st); const int oi2 = __shfl_xor(i2, st);
            merge2(v1, i1, v2, i2, o1, oi1, o2, oi2);
        }
        int cnt = 0;
        #pragma unroll
        for (int n = 0; n < 4; ++n) cnt += (v[n] > v2 - TAU) ? 1 : 0;
        cnt += __shfl_xor(cnt, 1);
        cnt += __shfl_xor(cnt, 2);
        cnt += __shfl_xor(cnt, 4);
        cnt += __shfl_xor(cnt, 8);

        const int T = tokBase + w * 16 + kg * 4 + r;
        if (rl == 0 && cnt > 2) {
            const unsigned int pos = atomicAdd(flagCnt, 1u);
            if (pos < TOKENS) flagList[pos] = T;
        }
        const float ex = expf(v2 - v1);      // <= 1
        const float w1 = 1.f / (1.f + ex);
        const float w2 = ex * w1;
        const int e0 = rl * 4;
        float4 o;
        o.x = (e0 + 0 == i1) ? w1 : ((e0 + 0 == i2) ? w2 : 0.f);
        o.y = (e0 + 1 == i1) ? w1 : ((e0 + 1 == i2) ? w2 : 0.f);
        o.z = (e0 + 2 == i1) ? w1 : ((e0 + 2 == i2) ? w2 : 0.f);
        o.w = (e0 + 3 == i1) ? w1 : ((e0 + 3 == i2) ? w2 : 0.f);
        *(float4*)(Out + (size_t)T * 64 + e0) = o;
    }
}

// ---- kernel 3: exact fp32 rescue for near-tie tokens ----
__launch_bounds__(64)
__global__ void rescue_kernel(const float* __restrict__ X,
                              const float* __restrict__ W,
                              const float* __restrict__ Bv,
                              float* __restrict__ Out,
                              const unsigned int* __restrict__ flagCnt,
                              const int* __restrict__ flagList) {
    __shared__ float sx[DDIM];
    const int lane = threadIdx.x;
    unsigned int n = *flagCnt;
    if (n > TOKENS) n = TOKENS;
    for (unsigned int i = blockIdx.x; i < n; i += gridDim.x) {
        const int t = flagList[i];
        __syncthreads();
        #pragma unroll
        for (int k = 0; k < 4; ++k)
            ((float4*)sx)[lane + 64 * k] =
                ((const float4*)(X + (size_t)t * DDIM))[lane + 64 * k];
        __syncthreads();
        float acc = Bv[lane];
        const float* wr = W + (size_t)lane * DDIM;
        #pragma unroll 4
        for (int d = 0; d < DDIM; d += 4) {
            const float4 wv = *(const float4*)(wr + d);
            acc = fmaf(sx[d + 0], wv.x, acc);
            acc = fmaf(sx[d + 1], wv.y, acc);
            acc = fmaf(sx[d + 2], wv.z, acc);
            acc = fmaf(sx[d + 3], wv.w, acc);
        }
        float v1 = acc, v2 = -INFINITY;
        int i1 = lane, i2 = 0x7fffffff;
        #pragma unroll
        for (int st = 1; st <= 32; st <<= 1) {
            const float o1 = __shfl_xor(v1, st); const int oi1 = __shfl_xor(i1, st);
            const float o2 = __shfl_xor(v2, st); const int oi2 = __shfl_xor(i2, st);
            merge2(v1, i1, v2, i2, o1, oi1, o2, oi2);
        }
        const float ex = expf(v2 - v1);
        const float w1 = 1.f / (1.f + ex);
        const float w2 = ex * w1;
        Out[(size_t)t * 64 + lane] = (lane == i1) ? w1 : ((lane == i2) ? w2 : 0.f);
    }
}

extern "C" void kernel_launch(void* const* d_in, const int* in_sizes, int n_in,
                              void* d_out, int out_size, void* d_ws, size_t ws_size,
                              hipStream_t stream) {
    const float* X  = (const float*)d_in[0];   // [32768, 1024]
    const float* W  = (const float*)d_in[1];   // [64, 1024]
    const float* Bv = (const float*)d_in[2];   // [64]
    float* Out = (float*)d_out;                // [32768, 64]

    unsigned char* ws = (unsigned char*)d_ws;
    unsigned int* cnt  = (unsigned int*)(ws + WS_CNT_OFF);
    int*          list = (int*)(ws + WS_LIST_OFF);
    unsigned int* Whi  = (unsigned int*)(ws + WS_WHI_OFF);
    unsigned int* Wlo  = (unsigned int*)(ws + WS_WLO_OFF);

    hipMemsetAsync(cnt, 0, 4, stream);
    hipLaunchKernelGGL(pack_w_kernel, dim3(32), dim3(256), 0, stream, W, Whi, Wlo);
    hipLaunchKernelGGL(router_mfma, dim3(TOKENS / 64), dim3(256), 0, stream,
                       X, Whi, Wlo, Bv, Out, cnt, list);
    hipLaunchKernelGGL(rescue_kernel, dim3(512), dim3(64), 0, stream,
                       X, W, Bv, Out, cnt, list);
}